// Round 15
// baseline (143.654 us; speedup 1.0000x reference)
//
#include <hip/hip_runtime.h>
#include <hip/hip_bf16.h>
#include <stdint.h>

#define NHEADS 12
#define HS 64
#define NB 8
#define NL 1024
#define ND 768
#define NE 1536
#define INFV 1000000000000.0f

typedef __bf16 bf16x8 __attribute__((ext_vector_type(8)));
typedef float f32x4 __attribute__((ext_vector_type(4)));

typedef __attribute__((address_space(1))) const unsigned int gas_uint;
typedef __attribute__((address_space(3))) unsigned int las_uint;
#define GLOAD_LDS16(g, l) __builtin_amdgcn_global_load_lds((gas_uint*)(g), (las_uint*)(l), 16, 0, 0)

__device__ __forceinline__ unsigned short f2bf(float f) {
  unsigned int u = __builtin_bit_cast(unsigned int, f);
  u += 0x7fffu + ((u >> 16) & 1u);   // round-to-nearest-even
  return (unsigned short)(u >> 16);
}

__device__ __forceinline__ bf16x8 load_frag(const unsigned short* p) {
  uint4 v = *(const uint4*)p;
  return __builtin_bit_cast(bf16x8, v);
}

// ---- prep: x->bf16 | W transpose->bf16 | rope trig table ----
__global__ __launch_bounds__(256) void k_prep(
    const float* __restrict__ x, const float* __restrict__ W,
    unsigned short* __restrict__ xb, unsigned short* __restrict__ wt,
    float* __restrict__ cst) {
  const int blk = blockIdx.x;
  if (blk < 6144) {
    int i = blk * 256 + threadIdx.x;
    float4 v = ((const float4*)x)[i];
    ushort4 o;
    o.x = f2bf(v.x); o.y = f2bf(v.y); o.z = f2bf(v.z); o.w = f2bf(v.w);
    ((ushort4*)xb)[i] = o;
  } else if (blk < 6144 + 288) {
    __shared__ float tile[64][65];
    int t = blk - 6144;
    int te = t % 24, td = t / 24;
    int c = threadIdx.x & 63, r4 = threadIdx.x >> 6;
    #pragma unroll
    for (int rr = 0; rr < 16; rr++) {
      int row = rr * 4 + r4;
      tile[row][c] = W[(size_t)(td * 64 + row) * NE + te * 64 + c];
    }
    __syncthreads();
    #pragma unroll
    for (int rr = 0; rr < 16; rr++) {
      int row = rr * 4 + r4;
      wt[(size_t)(te * 64 + row) * ND + td * 64 + c] = f2bf(tile[c][row]);
    }
  } else {
    int t = (blk - 6432) * 256 + threadIdx.x;   // 32768 = 1024*32
    int p = t >> 5, i = t & 31;
    float inv = powf(10000.0f, -(float)i / 32.0f);
    float sv, cv;
    sincosf((float)p * inv, &sv, &cv);
    cst[(p * 32 + i) * 2 + 0] = cv;
    cst[(p * 32 + i) * 2 + 1] = sv;
  }
}

// ---- device helper: one below-diagonal fill tile (v=0 mask arithmetic) ----
__device__ __forceinline__ void dev_fill_tile(int e, const int* __restrict__ mask,
                                              float* __restrict__ out, int tid) {
  const int bh = e / 28;
  int u = e % 28;
  int tm = 1;
  #pragma unroll
  for (int kk = 0; kk < 6; kk++) if (u >= tm) { u -= tm; tm++; }
  const int tn = u;                        // tn < tm
  const int b  = bh / NHEADS;
  const int* mrow = mask + b * NL;
  const int n0 = tn * 128 + (tid & 31) * 4;
  int4 mc = *(const int4*)&mrow[n0];
  float o0 = ((mc.x ? 0.0f : -INFV) - INFV) * 0.125f;
  float o1 = ((mc.y ? 0.0f : -INFV) - INFV) * 0.125f;
  float o2 = ((mc.z ? 0.0f : -INFV) - INFV) * 0.125f;
  float o3 = ((mc.w ? 0.0f : -INFV) - INFV) * 0.125f;
  const float oz = (-2.0f * INFV) * 0.125f;
  #pragma unroll
  for (int it = 0; it < 16; it++) {
    int m = tm * 128 + it * 8 + (tid >> 5);
    bool mr1 = (mrow[m] != 0);
    f32x4 o;
    o[0] = mr1 ? o0 : oz;
    o[1] = mr1 ? o1 : oz;
    o[2] = mr1 ? o2 : oz;
    o[3] = mr1 ? o3 : oz;
    __builtin_nontemporal_store(o, (f32x4*)(out + ((size_t)bh * NL + m) * NL + n0));
  }
}

// ---- device helper: one proj tile (128m x 128e) for (mt, h) ----
__device__ __forceinline__ void dev_proj_tile(
    int mt, int h, int tid, char* smem_b,
    const unsigned short* __restrict__ xb, const unsigned short* __restrict__ wt,
    const float* __restrict__ bias, const float* __restrict__ cst,
    unsigned short* __restrict__ qbuf, unsigned short* __restrict__ kbuf) {
  const int m0  = mt * 128;
  const int e0  = h * 128;
  const int lane = tid & 63;
  const int w    = tid >> 6;
  const int wm = w >> 1, wn = w & 1;
  const int col_l = lane & 15, rq = lane >> 4;

  unsigned int goff[4];
  #pragma unroll
  for (int q = 0; q < 4; q++) {
    int p = q * 256 + tid;
    int r = p >> 3, sl = p & 7;
    goff[q] = r * ND + (sl ^ (r & 7)) * 8;   // pre-swizzled source
  }
  const unsigned short* gA = wt + (size_t)e0 * ND;
  const unsigned short* gB = xb + (size_t)m0 * ND;

  const int xr = col_l & 7;
  const unsigned int aRow = (unsigned)((wn * 64 + col_l) * 128);
  const unsigned int bRow = (unsigned)(16384 + (wm * 64 + col_l) * 128);

  f32x4 acc[4][4];   // [e-frag][m-frag]
  #pragma unroll
  for (int i = 0; i < 4; i++)
    #pragma unroll
    for (int j = 0; j < 4; j++)
      #pragma unroll
      for (int q = 0; q < 4; q++) acc[i][j][q] = 0.0f;

  for (int kk = 0; kk < ND; kk += 64) {
    const unsigned short* sA = gA + kk;
    const unsigned short* sB = gB + kk;
    #pragma unroll
    for (int q = 0; q < 4; q++) GLOAD_LDS16(sA + goff[q], smem_b + (q * 256 + tid) * 16);
    #pragma unroll
    for (int q = 0; q < 4; q++) GLOAD_LDS16(sB + goff[q], smem_b + 16384 + (q * 256 + tid) * 16);
    __syncthreads();
    #pragma unroll
    for (int kkh = 0; kkh < 2; kkh++) {
      bf16x8 af[4], bfr[4];
      #pragma unroll
      for (int f = 0; f < 4; f++) {
        const unsigned int so = (((kkh << 2) | rq) ^ xr) * 16;
        af[f]  = __builtin_bit_cast(bf16x8, *(const uint4*)(smem_b + aRow + f * 2048 + so));
        bfr[f] = __builtin_bit_cast(bf16x8, *(const uint4*)(smem_b + bRow + f * 2048 + so));
      }
      #pragma unroll
      for (int i = 0; i < 4; i++)
        #pragma unroll
        for (int j = 0; j < 4; j++)
          acc[i][j] = __builtin_amdgcn_mfma_f32_16x16x32_bf16(af[i], bfr[j], acc[i][j], 0, 0, 0);
    }
    __syncthreads();
  }

  unsigned short* obuf = (wn == 1) ? kbuf : qbuf;   // wave-uniform
  #pragma unroll
  for (int j = 0; j < 4; j++) {
    const int m   = m0 + wm * 64 + j * 16 + col_l;
    const int pos = m & (NL - 1);
    const int bb  = m >> 10;
    const float* crow = cst + pos * 64;
    unsigned short* orow = obuf + (((size_t)(bb * NHEADS + h)) * NL + pos) * HS;
    #pragma unroll
    for (int i = 0; i < 4; i++) {
      const int s0 = i * 16 + rq * 4;
      float4 bv = *(const float4*)&bias[e0 + wn * 64 + s0];
      float4 tq = *(const float4*)(crow + s0);
      float v0 = acc[i][j][0] + bv.x;
      float v1 = acc[i][j][1] + bv.y;
      float v2 = acc[i][j][2] + bv.z;
      float v3 = acc[i][j][3] + bv.w;
      ushort4 o;
      o.x = f2bf(v0 * tq.x - v1 * tq.y);
      o.y = f2bf(v1 * tq.x + v0 * tq.y);
      o.z = f2bf(v2 * tq.z - v3 * tq.w);
      o.w = f2bf(v3 * tq.z + v2 * tq.w);
      *(ushort4*)&orow[s0] = o;
    }
  }
}

// ---- device helper: one upper-triangle logits tile (bh, u in [0,36)) ----
__device__ __forceinline__ void dev_logits_tile(
    int bh, int u, int tid, float* lds,
    const unsigned short* __restrict__ qbuf, const unsigned short* __restrict__ kbuf,
    const int* __restrict__ mask, float* __restrict__ out) {
  int tm = 0;
  #pragma unroll
  for (int k = 0; k < 7; k++) if (u >= 8 - tm) { u -= 8 - tm; tm++; }
  const int tn = tm + u;
  const int b  = bh / NHEADS;
  const int* mrow = mask + b * NL;

  const int lane = tid & 63;
  const int w    = tid >> 6;
  const int wm = w >> 1, wn = w & 1;
  const int m_base = tm * 128 + wm * 64;
  const int n_base = tn * 128 + wn * 64;
  const int col_l = lane & 15, rq = lane >> 4;
  const unsigned short* Q = qbuf + (size_t)bh * (NL * HS);
  const unsigned short* K = kbuf + (size_t)bh * (NL * HS);

  f32x4 acc[4][4];   // [n-frag][m-frag]
  #pragma unroll
  for (int i = 0; i < 4; i++)
    #pragma unroll
    for (int j = 0; j < 4; j++)
      #pragma unroll
      for (int q = 0; q < 4; q++) acc[i][j][q] = 0.0f;

  #pragma unroll
  for (int ks = 0; ks < 2; ks++) {
    bf16x8 ak[4], bq[4];
    #pragma unroll
    for (int ff = 0; ff < 4; ff++) {
      ak[ff] = load_frag(K + (size_t)(n_base + ff * 16 + col_l) * HS + ks * 32 + rq * 8);
      bq[ff] = load_frag(Q + (size_t)(m_base + ff * 16 + col_l) * HS + ks * 32 + rq * 8);
    }
    #pragma unroll
    for (int i = 0; i < 4; i++)
      #pragma unroll
      for (int j = 0; j < 4; j++)
        acc[i][j] = __builtin_amdgcn_mfma_f32_16x16x32_bf16(ak[i], bq[j], acc[i][j], 0, 0, 0);
  }

  const bool diag = (tn == tm);
  const int rb_row = tid >> 5;
  const int rb_c4  = (tid & 31) * 4;
  const int n_rb   = tn * 128 + rb_c4;
  int4 mc_rb = *(const int4*)&mrow[n_rb];
  const bool allmc = (mc_rb.x & mc_rb.y & mc_rb.z & mc_rb.w) != 0;

  #pragma unroll
  for (int pass = 0; pass < 2; pass++) {
    if (wm == pass) {
      #pragma unroll
      for (int j = 0; j < 4; j++) {
        const int rl = j * 16 + col_l;
        const int sw = (rl & 7) << 2;
        #pragma unroll
        for (int i = 0; i < 4; i++) {
          const int c = (wn * 64 + i * 16 + rq * 4) ^ sw;
          *(f32x4*)&lds[rl * 128 + c] = acc[i][j];
        }
      }
    }
    __syncthreads();
    #pragma unroll
    for (int it = 0; it < 8; it++) {
      const int rl = it * 8 + rb_row;
      const int m  = tm * 128 + pass * 64 + rl;
      const int c  = rb_c4 ^ ((rl & 7) << 2);
      f32x4 v = *(const f32x4*)&lds[rl * 128 + c];
      if (mrow[m] == 0) { v[0] = -INFV; v[1] = -INFV; v[2] = -INFV; v[3] = -INFV; }
      if (!allmc) {
        if (mc_rb.x == 0) v[0] = -INFV;
        if (mc_rb.y == 0) v[1] = -INFV;
        if (mc_rb.z == 0) v[2] = -INFV;
        if (mc_rb.w == 0) v[3] = -INFV;
      }
      if (diag) {
        if (n_rb + 0 < m) v[0] -= INFV;
        if (n_rb + 1 < m) v[1] -= INFV;
        if (n_rb + 2 < m) v[2] -= INFV;
        if (n_rb + 3 < m) v[3] -= INFV;
      }
      v *= 0.125f;
      __builtin_nontemporal_store(v, (f32x4*)(out + ((size_t)bh * NL + m) * NL + n_rb));
    }
    __syncthreads();
  }
}

// ---- pipelined chunk kernel: [proj | logits | fill] roles by blockIdx ----
// proj blocks first (start compute immediately), then logits (write-bound),
// then fills. Dependencies resolved at launch boundaries only.
__global__ __launch_bounds__(256, 4) void k_pipe(
    const unsigned short* __restrict__ xb, const unsigned short* __restrict__ wt,
    const float* __restrict__ bias, const float* __restrict__ cst,
    unsigned short* __restrict__ qbuf, unsigned short* __restrict__ kbuf,
    const int* __restrict__ mask, float* __restrict__ out,
    int nproj, int mt_base, int nlog, int bh_base, int fill_base) {
  __shared__ char smem_b[32768];
  const int tid = threadIdx.x;
  const int blk = blockIdx.x;

  if (blk < nproj) {
    // 192 proj tiles: per-XCD 2 m-tiles x 12 heads (x-tile L2 reuse)
    const int xcd = blk & 7;
    const int j   = blk >> 3;                // 0..23
    const int mt  = mt_base + xcd * 2 + j / 12;
    const int h   = j % 12;
    dev_proj_tile(mt, h, tid, smem_b, xb, wt, bias, cst, qbuf, kbuf);
  } else if (blk < nproj + nlog) {
    // 864 logits tiles: 24 bh x 36 upper-triangle tiles, XCD-grouped by bh
    const int i = blk - nproj;
    const int r = i & 7, t = i >> 3;
    const int bh = bh_base + r + 8 * (t / 36);
    dev_logits_tile(bh, t % 36, tid, (float*)smem_b, qbuf, kbuf, mask, out);
  } else {
    dev_fill_tile(fill_base + (blk - nproj - nlog), mask, out, tid);
  }
}

extern "C" void kernel_launch(void* const* d_in, const int* in_sizes, int n_in,
                              void* d_out, int out_size, void* d_ws, size_t ws_size,
                              hipStream_t stream) {
  const float* x    = (const float*)d_in[0];
  const float* W    = (const float*)d_in[1];
  const float* bias = (const float*)d_in[2];
  const int*   mask = (const int*)d_in[3];
  float* out = (float*)d_out;
  char* ws = (char*)d_ws;

  unsigned short* xb = (unsigned short*)(ws);              // 12,582,912 B
  unsigned short* wt = (unsigned short*)(ws + 12582912);   //  2,359,296 B
  unsigned short* qb = (unsigned short*)(ws + 14942208);   // 12,582,912 B
  unsigned short* kb = (unsigned short*)(ws + 27525120);   // 12,582,912 B
  float* cst = (float*)(ws + 40108032);                    //    262,144 B

  k_prep<<<6560, 256, 0, stream>>>(x, W, xb, wt, cst);

  // C1: proj(b0,b1) + fills[0,538)
  k_pipe<<<192 + 0 + 538, 256, 0, stream>>>(xb, wt, bias, cst, qb, kb, mask, out,
                                            192, 0, 0, 0, 0);
  // C2: proj(b2,b3) + logits(b0,b1) + fills[538,1076)
  k_pipe<<<192 + 864 + 538, 256, 0, stream>>>(xb, wt, bias, cst, qb, kb, mask, out,
                                              192, 16, 864, 0, 538);
  // C3: proj(b4,b5) + logits(b2,b3) + fills[1076,1614)
  k_pipe<<<192 + 864 + 538, 256, 0, stream>>>(xb, wt, bias, cst, qb, kb, mask, out,
                                              192, 32, 864, 24, 1076);
  // C4: proj(b6,b7) + logits(b4,b5) + fills[1614,2152)
  k_pipe<<<192 + 864 + 538, 256, 0, stream>>>(xb, wt, bias, cst, qb, kb, mask, out,
                                              192, 48, 864, 48, 1614);
  // C5: logits(b6,b7) + fills[2152,2688)
  k_pipe<<<0 + 864 + 536, 256, 0, stream>>>(xb, wt, bias, cst, qb, kb, mask, out,
                                            0, 0, 864, 72, 2152);
}

// Round 16
// 126.873 us; speedup vs baseline: 1.1323x; 1.1323x over previous
//
#include <hip/hip_runtime.h>
#include <hip/hip_bf16.h>
#include <stdint.h>

#define NHEADS 12
#define HS 64
#define NB 8
#define NL 1024
#define ND 768
#define NE 1536
#define INFV 1000000000000.0f

typedef __bf16 bf16x8 __attribute__((ext_vector_type(8)));
typedef float f32x4 __attribute__((ext_vector_type(4)));

typedef __attribute__((address_space(1))) const unsigned int gas_uint;
typedef __attribute__((address_space(3))) unsigned int las_uint;
#define GLOAD_LDS16(g, l) __builtin_amdgcn_global_load_lds((gas_uint*)(g), (las_uint*)(l), 16, 0, 0)

__device__ __forceinline__ unsigned short f2bf(float f) {
  unsigned int u = __builtin_bit_cast(unsigned int, f);
  u += 0x7fffu + ((u >> 16) & 1u);   // round-to-nearest-even
  return (unsigned short)(u >> 16);
}

__device__ __forceinline__ bf16x8 load_frag(const unsigned short* p) {
  uint4 v = *(const uint4*)p;
  return __builtin_bit_cast(bf16x8, v);
}

// ---- prep: x->bf16 | W transpose->bf16 | rope trig table ----
__global__ __launch_bounds__(256) void k_prep(
    const float* __restrict__ x, const float* __restrict__ W,
    unsigned short* __restrict__ xb, unsigned short* __restrict__ wt,
    float* __restrict__ cst) {
  const int blk = blockIdx.x;
  if (blk < 6144) {
    int i = blk * 256 + threadIdx.x;
    float4 v = ((const float4*)x)[i];
    ushort4 o;
    o.x = f2bf(v.x); o.y = f2bf(v.y); o.z = f2bf(v.z); o.w = f2bf(v.w);
    ((ushort4*)xb)[i] = o;
  } else if (blk < 6144 + 288) {
    __shared__ float tile[64][65];
    int t = blk - 6144;
    int te = t % 24, td = t / 24;
    int c = threadIdx.x & 63, r4 = threadIdx.x >> 6;
    #pragma unroll
    for (int rr = 0; rr < 16; rr++) {
      int row = rr * 4 + r4;
      tile[row][c] = W[(size_t)(td * 64 + row) * NE + te * 64 + c];
    }
    __syncthreads();
    #pragma unroll
    for (int rr = 0; rr < 16; rr++) {
      int row = rr * 4 + r4;
      wt[(size_t)(te * 64 + row) * ND + td * 64 + c] = f2bf(tile[c][row]);
    }
  } else {
    int t = (blk - 6432) * 256 + threadIdx.x;   // 32768 = 1024*32
    int p = t >> 5, i = t & 31;
    float inv = powf(10000.0f, -(float)i / 32.0f);
    float sv, cv;
    sincosf((float)p * inv, &sv, &cv);
    cst[(p * 32 + i) * 2 + 0] = cv;
    cst[(p * 32 + i) * 2 + 1] = sv;
  }
}

// ---- device helper: one below-diagonal fill tile (v=0 mask arithmetic) ----
__device__ __forceinline__ void dev_fill_tile(int e, const int* __restrict__ mask,
                                              float* __restrict__ out, int tid) {
  const int bh = e / 28;
  int u = e % 28;
  int tm = 1;
  #pragma unroll
  for (int kk = 0; kk < 6; kk++) if (u >= tm) { u -= tm; tm++; }
  const int tn = u;                        // tn < tm
  const int b  = bh / NHEADS;
  const int* mrow = mask + b * NL;
  const int n0 = tn * 128 + (tid & 31) * 4;
  int4 mc = *(const int4*)&mrow[n0];
  float o0 = ((mc.x ? 0.0f : -INFV) - INFV) * 0.125f;
  float o1 = ((mc.y ? 0.0f : -INFV) - INFV) * 0.125f;
  float o2 = ((mc.z ? 0.0f : -INFV) - INFV) * 0.125f;
  float o3 = ((mc.w ? 0.0f : -INFV) - INFV) * 0.125f;
  const float oz = (-2.0f * INFV) * 0.125f;
  #pragma unroll
  for (int it = 0; it < 16; it++) {
    int m = tm * 128 + it * 8 + (tid >> 5);
    bool mr1 = (mrow[m] != 0);
    f32x4 o;
    o[0] = mr1 ? o0 : oz;
    o[1] = mr1 ? o1 : oz;
    o[2] = mr1 ? o2 : oz;
    o[3] = mr1 ? o3 : oz;
    __builtin_nontemporal_store(o, (f32x4*)(out + ((size_t)bh * NL + m) * NL + n0));
  }
}

// ---- device helper: one proj tile (128m x 128e) for (mt, h) ----
__device__ __forceinline__ void dev_proj_tile(
    int mt, int h, int tid, char* smem_b,
    const unsigned short* __restrict__ xb, const unsigned short* __restrict__ wt,
    const float* __restrict__ bias, const float* __restrict__ cst,
    unsigned short* __restrict__ qbuf, unsigned short* __restrict__ kbuf) {
  const int m0  = mt * 128;
  const int e0  = h * 128;
  const int lane = tid & 63;
  const int w    = tid >> 6;
  const int wm = w >> 1, wn = w & 1;
  const int col_l = lane & 15, rq = lane >> 4;

  unsigned int goff[4];
  #pragma unroll
  for (int q = 0; q < 4; q++) {
    int p = q * 256 + tid;
    int r = p >> 3, sl = p & 7;
    goff[q] = r * ND + (sl ^ (r & 7)) * 8;   // pre-swizzled source
  }
  const unsigned short* gA = wt + (size_t)e0 * ND;
  const unsigned short* gB = xb + (size_t)m0 * ND;

  const int xr = col_l & 7;
  const unsigned int aRow = (unsigned)((wn * 64 + col_l) * 128);
  const unsigned int bRow = (unsigned)(16384 + (wm * 64 + col_l) * 128);

  f32x4 acc[4][4];   // [e-frag][m-frag]
  #pragma unroll
  for (int i = 0; i < 4; i++)
    #pragma unroll
    for (int j = 0; j < 4; j++)
      #pragma unroll
      for (int q = 0; q < 4; q++) acc[i][j][q] = 0.0f;

  for (int kk = 0; kk < ND; kk += 64) {
    const unsigned short* sA = gA + kk;
    const unsigned short* sB = gB + kk;
    #pragma unroll
    for (int q = 0; q < 4; q++) GLOAD_LDS16(sA + goff[q], smem_b + (q * 256 + tid) * 16);
    #pragma unroll
    for (int q = 0; q < 4; q++) GLOAD_LDS16(sB + goff[q], smem_b + 16384 + (q * 256 + tid) * 16);
    __syncthreads();
    #pragma unroll
    for (int kkh = 0; kkh < 2; kkh++) {
      bf16x8 af[4], bfr[4];
      #pragma unroll
      for (int f = 0; f < 4; f++) {
        const unsigned int so = (((kkh << 2) | rq) ^ xr) * 16;
        af[f]  = __builtin_bit_cast(bf16x8, *(const uint4*)(smem_b + aRow + f * 2048 + so));
        bfr[f] = __builtin_bit_cast(bf16x8, *(const uint4*)(smem_b + bRow + f * 2048 + so));
      }
      #pragma unroll
      for (int i = 0; i < 4; i++)
        #pragma unroll
        for (int j = 0; j < 4; j++)
          acc[i][j] = __builtin_amdgcn_mfma_f32_16x16x32_bf16(af[i], bfr[j], acc[i][j], 0, 0, 0);
    }
    __syncthreads();
  }

  unsigned short* obuf = (wn == 1) ? kbuf : qbuf;   // wave-uniform
  #pragma unroll
  for (int j = 0; j < 4; j++) {
    const int m   = m0 + wm * 64 + j * 16 + col_l;
    const int pos = m & (NL - 1);
    const int bb  = m >> 10;
    const float* crow = cst + pos * 64;
    unsigned short* orow = obuf + (((size_t)(bb * NHEADS + h)) * NL + pos) * HS;
    #pragma unroll
    for (int i = 0; i < 4; i++) {
      const int s0 = i * 16 + rq * 4;
      float4 bv = *(const float4*)&bias[e0 + wn * 64 + s0];
      float4 tq = *(const float4*)(crow + s0);
      float v0 = acc[i][j][0] + bv.x;
      float v1 = acc[i][j][1] + bv.y;
      float v2 = acc[i][j][2] + bv.z;
      float v3 = acc[i][j][3] + bv.w;
      ushort4 o;
      o.x = f2bf(v0 * tq.x - v1 * tq.y);
      o.y = f2bf(v1 * tq.x + v0 * tq.y);
      o.z = f2bf(v2 * tq.z - v3 * tq.w);
      o.w = f2bf(v3 * tq.z + v2 * tq.w);
      *(ushort4*)&orow[s0] = o;
    }
  }
}

// ---- device helper: one upper-triangle logits tile (bh, u in [0,36)) ----
__device__ __forceinline__ void dev_logits_tile(
    int bh, int u, int tid, float* lds,
    const unsigned short* __restrict__ qbuf, const unsigned short* __restrict__ kbuf,
    const int* __restrict__ mask, float* __restrict__ out) {
  int tm = 0;
  #pragma unroll
  for (int k = 0; k < 7; k++) if (u >= 8 - tm) { u -= 8 - tm; tm++; }
  const int tn = tm + u;
  const int b  = bh / NHEADS;
  const int* mrow = mask + b * NL;

  const int lane = tid & 63;
  const int w    = tid >> 6;
  const int wm = w >> 1, wn = w & 1;
  const int m_base = tm * 128 + wm * 64;
  const int n_base = tn * 128 + wn * 64;
  const int col_l = lane & 15, rq = lane >> 4;
  const unsigned short* Q = qbuf + (size_t)bh * (NL * HS);
  const unsigned short* K = kbuf + (size_t)bh * (NL * HS);

  f32x4 acc[4][4];   // [n-frag][m-frag]
  #pragma unroll
  for (int i = 0; i < 4; i++)
    #pragma unroll
    for (int j = 0; j < 4; j++)
      #pragma unroll
      for (int q = 0; q < 4; q++) acc[i][j][q] = 0.0f;

  #pragma unroll
  for (int ks = 0; ks < 2; ks++) {
    bf16x8 ak[4], bq[4];
    #pragma unroll
    for (int ff = 0; ff < 4; ff++) {
      ak[ff] = load_frag(K + (size_t)(n_base + ff * 16 + col_l) * HS + ks * 32 + rq * 8);
      bq[ff] = load_frag(Q + (size_t)(m_base + ff * 16 + col_l) * HS + ks * 32 + rq * 8);
    }
    #pragma unroll
    for (int i = 0; i < 4; i++)
      #pragma unroll
      for (int j = 0; j < 4; j++)
        acc[i][j] = __builtin_amdgcn_mfma_f32_16x16x32_bf16(ak[i], bq[j], acc[i][j], 0, 0, 0);
  }

  const bool diag = (tn == tm);
  const int rb_row = tid >> 5;
  const int rb_c4  = (tid & 31) * 4;
  const int n_rb   = tn * 128 + rb_c4;
  int4 mc_rb = *(const int4*)&mrow[n_rb];
  const bool allmc = (mc_rb.x & mc_rb.y & mc_rb.z & mc_rb.w) != 0;

  #pragma unroll
  for (int pass = 0; pass < 2; pass++) {
    if (wm == pass) {
      #pragma unroll
      for (int j = 0; j < 4; j++) {
        const int rl = j * 16 + col_l;
        const int sw = (rl & 7) << 2;
        #pragma unroll
        for (int i = 0; i < 4; i++) {
          const int c = (wn * 64 + i * 16 + rq * 4) ^ sw;
          *(f32x4*)&lds[rl * 128 + c] = acc[i][j];
        }
      }
    }
    __syncthreads();
    #pragma unroll
    for (int it = 0; it < 8; it++) {
      const int rl = it * 8 + rb_row;
      const int m  = tm * 128 + pass * 64 + rl;
      const int c  = rb_c4 ^ ((rl & 7) << 2);
      f32x4 v = *(const f32x4*)&lds[rl * 128 + c];
      if (mrow[m] == 0) { v[0] = -INFV; v[1] = -INFV; v[2] = -INFV; v[3] = -INFV; }
      if (!allmc) {
        if (mc_rb.x == 0) v[0] = -INFV;
        if (mc_rb.y == 0) v[1] = -INFV;
        if (mc_rb.z == 0) v[2] = -INFV;
        if (mc_rb.w == 0) v[3] = -INFV;
      }
      if (diag) {
        if (n_rb + 0 < m) v[0] -= INFV;
        if (n_rb + 1 < m) v[1] -= INFV;
        if (n_rb + 2 < m) v[2] -= INFV;
        if (n_rb + 3 < m) v[3] -= INFV;
      }
      v *= 0.125f;
      __builtin_nontemporal_store(v, (f32x4*)(out + ((size_t)bh * NL + m) * NL + n_rb));
    }
    __syncthreads();
  }
}

// ---- fat-chunk pipeline kernel: [proj | logits | fill] roles by blockIdx ----
// proj blocks first (compute starts immediately and hides under the write
// streams of the logits/fill blocks). Deps resolved at launch boundaries.
__global__ __launch_bounds__(256, 4) void k_pipe(
    const unsigned short* __restrict__ xb, const unsigned short* __restrict__ wt,
    const float* __restrict__ bias, const float* __restrict__ cst,
    unsigned short* __restrict__ qbuf, unsigned short* __restrict__ kbuf,
    const int* __restrict__ mask, float* __restrict__ out,
    int nproj, int mt_base, int nlog, int bh_base, int fill_base) {
  __shared__ char smem_b[32768];
  const int tid = threadIdx.x;
  const int blk = blockIdx.x;

  if (blk < nproj) {
    // 384 proj tiles: per-XCD 4 m-tiles x 12 heads (x-tile L2 reuse)
    const int xcd = blk & 7;
    const int j   = blk >> 3;                // 0..47
    const int mt  = mt_base + xcd * 4 + j / 12;
    const int h   = j % 12;
    dev_proj_tile(mt, h, tid, smem_b, xb, wt, bias, cst, qbuf, kbuf);
  } else if (blk < nproj + nlog) {
    // 1728 logits tiles: 48 bh x 36 upper-triangle tiles, XCD-grouped by bh
    const int i = blk - nproj;
    const int r = i & 7, t = i >> 3;
    const int bh = bh_base + r + 8 * (t / 36);
    dev_logits_tile(bh, t % 36, tid, (float*)smem_b, qbuf, kbuf, mask, out);
  } else {
    dev_fill_tile(fill_base + (blk - nproj - nlog), mask, out, tid);
  }
}

extern "C" void kernel_launch(void* const* d_in, const int* in_sizes, int n_in,
                              void* d_out, int out_size, void* d_ws, size_t ws_size,
                              hipStream_t stream) {
  const float* x    = (const float*)d_in[0];
  const float* W    = (const float*)d_in[1];
  const float* bias = (const float*)d_in[2];
  const int*   mask = (const int*)d_in[3];
  float* out = (float*)d_out;
  char* ws = (char*)d_ws;

  unsigned short* xb = (unsigned short*)(ws);              // 12,582,912 B
  unsigned short* wt = (unsigned short*)(ws + 12582912);   //  2,359,296 B
  unsigned short* qb = (unsigned short*)(ws + 14942208);   // 12,582,912 B
  unsigned short* kb = (unsigned short*)(ws + 27525120);   // 12,582,912 B
  float* cst = (float*)(ws + 40108032);                    //    262,144 B

  k_prep<<<6560, 256, 0, stream>>>(x, W, xb, wt, cst);

  // C1: proj(b0..b3) + ALL fills
  k_pipe<<<384 + 0 + 2688, 256, 0, stream>>>(xb, wt, bias, cst, qb, kb, mask, out,
                                             384, 0, 0, 0, 0);
  // C2: proj(b4..b7) + logits(b0..b3)
  k_pipe<<<384 + 1728 + 0, 256, 0, stream>>>(xb, wt, bias, cst, qb, kb, mask, out,
                                             384, 32, 1728, 0, 0);
  // C3: logits(b4..b7)
  k_pipe<<<0 + 1728 + 0, 256, 0, stream>>>(xb, wt, bias, cst, qb, kb, mask, out,
                                           0, 0, 1728, 48, 0);
}

// Round 17
// 119.855 us; speedup vs baseline: 1.1986x; 1.0586x over previous
//
#include <hip/hip_runtime.h>
#include <hip/hip_bf16.h>
#include <stdint.h>

#define NHEADS 12
#define HS 64
#define NB 8
#define NL 1024
#define ND 768
#define NE 1536
#define INFV 1000000000000.0f

typedef __bf16 bf16x8 __attribute__((ext_vector_type(8)));
typedef float f32x4 __attribute__((ext_vector_type(4)));

typedef __attribute__((address_space(1))) const unsigned int gas_uint;
typedef __attribute__((address_space(3))) unsigned int las_uint;
#define GLOAD_LDS16(g, l) __builtin_amdgcn_global_load_lds((gas_uint*)(g), (las_uint*)(l), 16, 0, 0)

__device__ __forceinline__ unsigned short f2bf(float f) {
  unsigned int u = __builtin_bit_cast(unsigned int, f);
  u += 0x7fffu + ((u >> 16) & 1u);   // round-to-nearest-even
  return (unsigned short)(u >> 16);
}

__device__ __forceinline__ bf16x8 load_frag(const unsigned short* p) {
  uint4 v = *(const uint4*)p;
  return __builtin_bit_cast(bf16x8, v);
}

// ---- prep: x->bf16 | W transpose->bf16 | rope trig table ----
__global__ __launch_bounds__(256) void k_prep(
    const float* __restrict__ x, const float* __restrict__ W,
    unsigned short* __restrict__ xb, unsigned short* __restrict__ wt,
    float* __restrict__ cst) {
  const int blk = blockIdx.x;
  if (blk < 6144) {
    int i = blk * 256 + threadIdx.x;
    float4 v = ((const float4*)x)[i];
    ushort4 o;
    o.x = f2bf(v.x); o.y = f2bf(v.y); o.z = f2bf(v.z); o.w = f2bf(v.w);
    ((ushort4*)xb)[i] = o;
  } else if (blk < 6144 + 288) {
    __shared__ float tile[64][65];
    int t = blk - 6144;
    int te = t % 24, td = t / 24;
    int c = threadIdx.x & 63, r4 = threadIdx.x >> 6;
    #pragma unroll
    for (int rr = 0; rr < 16; rr++) {
      int row = rr * 4 + r4;
      tile[row][c] = W[(size_t)(td * 64 + row) * NE + te * 64 + c];
    }
    __syncthreads();
    #pragma unroll
    for (int rr = 0; rr < 16; rr++) {
      int row = rr * 4 + r4;
      wt[(size_t)(te * 64 + row) * ND + td * 64 + c] = f2bf(tile[c][row]);
    }
  } else {
    int t = (blk - 6432) * 256 + threadIdx.x;   // 32768 = 1024*32
    int p = t >> 5, i = t & 31;
    float inv = powf(10000.0f, -(float)i / 32.0f);
    float sv, cv;
    sincosf((float)p * inv, &sv, &cv);
    cst[(p * 32 + i) * 2 + 0] = cv;
    cst[(p * 32 + i) * 2 + 1] = sv;
  }
}

// ---- proj (256m x 128e tiles, 512 thr) + below-diag fills, one launch ----
// Proj: blocks 0..383. A (W^T rows, one head = 128 e) 16 KB; B (x rows, 256 m)
// 32 KB; BK=64; XOR-swizzled staging (slot^(row&7), pre-swizzled source).
// 8 waves, each 128m x 32e: acc[2][8], b-frag loaded in j-loop (VGPR<=128).
// Fills: blocks 384+, 512-thread NT-store stream, co-resident with proj.
__global__ __launch_bounds__(512, 4) void k_projfill(
    const unsigned short* __restrict__ xb,   // [8192][768] bf16
    const unsigned short* __restrict__ wt,   // [1536][768] bf16 (W^T)
    const float* __restrict__ bias,          // [1536]
    const float* __restrict__ cst,           // [1024][32] float2 (c,s)
    unsigned short* __restrict__ qbuf, unsigned short* __restrict__ kbuf,
    const int* __restrict__ mask, float* __restrict__ out) {
  __shared__ char smem_b[49152];             // A 16K | B 32K
  const int tid = threadIdx.x;               // 0..511
  const int blk = blockIdx.x;

  if (blk >= 384) {
    // ---- fill path: one below-diagonal 128x128 tile, 512 threads ----
    const int e   = blk - 384;               // 0..2687
    const int bh  = e / 28;
    int u = e % 28;
    int tm = 1;
    #pragma unroll
    for (int kk = 0; kk < 6; kk++) if (u >= tm) { u -= tm; tm++; }
    const int tn = u;                        // tn < tm
    const int b  = bh / NHEADS;
    const int* mrow = mask + b * NL;
    const int n0 = tn * 128 + (tid & 31) * 4;
    const int row = tid >> 5;                // 0..15
    int4 mc = *(const int4*)&mrow[n0];
    float o0 = ((mc.x ? 0.0f : -INFV) - INFV) * 0.125f;
    float o1 = ((mc.y ? 0.0f : -INFV) - INFV) * 0.125f;
    float o2 = ((mc.z ? 0.0f : -INFV) - INFV) * 0.125f;
    float o3 = ((mc.w ? 0.0f : -INFV) - INFV) * 0.125f;
    const float oz = (-2.0f * INFV) * 0.125f;
    #pragma unroll
    for (int it = 0; it < 8; it++) {
      int m = tm * 128 + it * 16 + row;
      bool mr1 = (mrow[m] != 0);
      f32x4 o;
      o[0] = mr1 ? o0 : oz;
      o[1] = mr1 ? o1 : oz;
      o[2] = mr1 ? o2 : oz;
      o[3] = mr1 ? o3 : oz;
      __builtin_nontemporal_store(o, (f32x4*)(out + ((size_t)bh * NL + m) * NL + n0));
    }
    return;
  }

  // ---- proj path ----
  const int xcd = blk & 7;
  const int loc = blk >> 3;                  // 0..47
  const int mt  = xcd * 4 + loc / 12;        // 32 m-tiles, 4 per XCD
  const int et  = loc % 12;                  // head index
  const int m0  = mt * 256;
  const int e0  = et * 128;
  const int lane = tid & 63;
  const int w    = tid >> 6;                 // 0..7
  const int wm = w >> 2, wn = w & 3;         // 2 m-halves x 4 e-quads
  const int col_l = lane & 15, rq = lane >> 4;

  unsigned int goffA[2], goffB[4];
  #pragma unroll
  for (int q = 0; q < 2; q++) {
    int p = q * 512 + tid;                   // 0..1023 (A: 128 rows x 8 slots)
    int r = p >> 3, sl = p & 7;
    goffA[q] = r * ND + (sl ^ (r & 7)) * 8;
  }
  #pragma unroll
  for (int q = 0; q < 4; q++) {
    int p = q * 512 + tid;                   // 0..2047 (B: 256 rows x 8 slots)
    int r = p >> 3, sl = p & 7;
    goffB[q] = r * ND + (sl ^ (r & 7)) * 8;
  }
  const unsigned short* gA = wt + (size_t)e0 * ND;
  const unsigned short* gB = xb + (size_t)m0 * ND;

  const int xr = col_l & 7;
  const unsigned int aRow = (unsigned)((wn * 32 + col_l) * 128);
  const unsigned int bRow = (unsigned)(16384 + (wm * 128 + col_l) * 128);

  f32x4 acc[2][8];   // [e-frag][m-frag]
  #pragma unroll
  for (int i = 0; i < 2; i++)
    #pragma unroll
    for (int j = 0; j < 8; j++)
      #pragma unroll
      for (int q = 0; q < 4; q++) acc[i][j][q] = 0.0f;

  for (int kk = 0; kk < ND; kk += 64) {
    const unsigned short* sA = gA + kk;
    const unsigned short* sB = gB + kk;
    #pragma unroll
    for (int q = 0; q < 2; q++) GLOAD_LDS16(sA + goffA[q], smem_b + (q * 512 + tid) * 16);
    #pragma unroll
    for (int q = 0; q < 4; q++) GLOAD_LDS16(sB + goffB[q], smem_b + 16384 + (q * 512 + tid) * 16);
    __syncthreads();
    #pragma unroll
    for (int kkh = 0; kkh < 2; kkh++) {
      const unsigned int so = (((kkh << 2) | rq) ^ xr) * 16;
      bf16x8 af0 = __builtin_bit_cast(bf16x8, *(const uint4*)(smem_b + aRow + 0 * 2048 + so));
      bf16x8 af1 = __builtin_bit_cast(bf16x8, *(const uint4*)(smem_b + aRow + 1 * 2048 + so));
      #pragma unroll
      for (int j = 0; j < 8; j++) {
        bf16x8 bfr = __builtin_bit_cast(bf16x8, *(const uint4*)(smem_b + bRow + j * 2048 + so));
        acc[0][j] = __builtin_amdgcn_mfma_f32_16x16x32_bf16(af0, bfr, acc[0][j], 0, 0, 0);
        acc[1][j] = __builtin_amdgcn_mfma_f32_16x16x32_bf16(af1, bfr, acc[1][j], 0, 0, 0);
      }
    }
    __syncthreads();
  }

  // epilogue: bias + rope; e-quad is wave-uniform q-or-k of head et
  const bool isk = (wn >= 2);
  unsigned short* obuf = isk ? kbuf : qbuf;
  #pragma unroll
  for (int j = 0; j < 8; j++) {
    const int m   = m0 + wm * 128 + j * 16 + col_l;
    const int pos = m & (NL - 1);
    const int bb  = m >> 10;
    const float* crow = cst + pos * 64;
    unsigned short* orow = obuf + (((size_t)(bb * NHEADS + et)) * NL + pos) * HS;
    #pragma unroll
    for (int i = 0; i < 2; i++) {
      const int sl0 = wn * 32 + i * 16 + rq * 4;   // 0..124 within head cols
      const int s0  = sl0 & 63;                    // head-dim offset
      float4 bv = *(const float4*)&bias[e0 + sl0];
      float4 tq = *(const float4*)(crow + s0);
      float v0 = acc[i][j][0] + bv.x;
      float v1 = acc[i][j][1] + bv.y;
      float v2 = acc[i][j][2] + bv.z;
      float v3 = acc[i][j][3] + bv.w;
      ushort4 o;
      o.x = f2bf(v0 * tq.x - v1 * tq.y);
      o.y = f2bf(v1 * tq.x + v0 * tq.y);
      o.z = f2bf(v2 * tq.z - v3 * tq.w);
      o.w = f2bf(v3 * tq.z + v2 * tq.w);
      *(ushort4*)&orow[s0] = o;
    }
  }
}

// ---- logits: upper-triangle (tn >= tm) tiles, per (b,h) Q @ K^T ----
__global__ __launch_bounds__(256) void k_logits(
    const unsigned short* __restrict__ qbuf,
    const unsigned short* __restrict__ kbuf,
    const int* __restrict__ mask,
    float* __restrict__ out) {
  const int f  = blockIdx.x;
  const int r  = f & 7, t = f >> 3;
  const int bh = r + 8 * (t / 36);
  int u = t % 36;
  int tm = 0;
  #pragma unroll
  for (int k = 0; k < 7; k++) if (u >= 8 - tm) { u -= 8 - tm; tm++; }
  const int tn = tm + u;
  const int b  = bh / NHEADS;
  const int tid  = threadIdx.x;
  const int* mrow = mask + b * NL;

  const int lane = tid & 63;
  const int w    = tid >> 6;
  const int wm = w >> 1, wn = w & 1;
  const int m_base = tm * 128 + wm * 64;
  const int n_base = tn * 128 + wn * 64;
  const int col_l = lane & 15, rq = lane >> 4;
  const unsigned short* Q = qbuf + (size_t)bh * (NL * HS);
  const unsigned short* K = kbuf + (size_t)bh * (NL * HS);

  __shared__ float lds[64 * 128];            // 32 KB, XOR-swizzled bounce

  f32x4 acc[4][4];   // [n-frag][m-frag]
  #pragma unroll
  for (int i = 0; i < 4; i++)
    #pragma unroll
    for (int j = 0; j < 4; j++)
      #pragma unroll
      for (int q = 0; q < 4; q++) acc[i][j][q] = 0.0f;

  #pragma unroll
  for (int ks = 0; ks < 2; ks++) {
    bf16x8 ak[4], bq[4];
    #pragma unroll
    for (int ff = 0; ff < 4; ff++) {
      ak[ff] = load_frag(K + (size_t)(n_base + ff * 16 + col_l) * HS + ks * 32 + rq * 8);
      bq[ff] = load_frag(Q + (size_t)(m_base + ff * 16 + col_l) * HS + ks * 32 + rq * 8);
    }
    #pragma unroll
    for (int i = 0; i < 4; i++)
      #pragma unroll
      for (int j = 0; j < 4; j++)
        acc[i][j] = __builtin_amdgcn_mfma_f32_16x16x32_bf16(ak[i], bq[j], acc[i][j], 0, 0, 0);
  }

  const bool diag = (tn == tm);
  const int rb_row = tid >> 5;
  const int rb_c4  = (tid & 31) * 4;
  const int n_rb   = tn * 128 + rb_c4;
  int4 mc_rb = *(const int4*)&mrow[n_rb];
  const bool allmc = (mc_rb.x & mc_rb.y & mc_rb.z & mc_rb.w) != 0;

  #pragma unroll
  for (int pass = 0; pass < 2; pass++) {
    if (wm == pass) {
      #pragma unroll
      for (int j = 0; j < 4; j++) {
        const int rl = j * 16 + col_l;
        const int sw = (rl & 7) << 2;
        #pragma unroll
        for (int i = 0; i < 4; i++) {
          const int c = (wn * 64 + i * 16 + rq * 4) ^ sw;
          *(f32x4*)&lds[rl * 128 + c] = acc[i][j];
        }
      }
    }
    __syncthreads();
    #pragma unroll
    for (int it = 0; it < 8; it++) {
      const int rl = it * 8 + rb_row;
      const int m  = tm * 128 + pass * 64 + rl;
      const int c  = rb_c4 ^ ((rl & 7) << 2);
      f32x4 v = *(const f32x4*)&lds[rl * 128 + c];
      if (mrow[m] == 0) { v[0] = -INFV; v[1] = -INFV; v[2] = -INFV; v[3] = -INFV; }
      if (!allmc) {
        if (mc_rb.x == 0) v[0] = -INFV;
        if (mc_rb.y == 0) v[1] = -INFV;
        if (mc_rb.z == 0) v[2] = -INFV;
        if (mc_rb.w == 0) v[3] = -INFV;
      }
      if (diag) {
        if (n_rb + 0 < m) v[0] -= INFV;
        if (n_rb + 1 < m) v[1] -= INFV;
        if (n_rb + 2 < m) v[2] -= INFV;
        if (n_rb + 3 < m) v[3] -= INFV;
      }
      v *= 0.125f;
      __builtin_nontemporal_store(v, (f32x4*)(out + ((size_t)bh * NL + m) * NL + n_rb));
    }
    __syncthreads();
  }
}

extern "C" void kernel_launch(void* const* d_in, const int* in_sizes, int n_in,
                              void* d_out, int out_size, void* d_ws, size_t ws_size,
                              hipStream_t stream) {
  const float* x    = (const float*)d_in[0];
  const float* W    = (const float*)d_in[1];
  const float* bias = (const float*)d_in[2];
  const int*   mask = (const int*)d_in[3];
  float* out = (float*)d_out;
  char* ws = (char*)d_ws;

  unsigned short* xb = (unsigned short*)(ws);              // 12,582,912 B
  unsigned short* wt = (unsigned short*)(ws + 12582912);   //  2,359,296 B
  unsigned short* qb = (unsigned short*)(ws + 14942208);   // 12,582,912 B
  unsigned short* kb = (unsigned short*)(ws + 27525120);   // 12,582,912 B
  float* cst = (float*)(ws + 40108032);                    //    262,144 B

  k_prep<<<6560, 256, 0, stream>>>(x, W, xb, wt, cst);
  k_projfill<<<384 + 2688, 512, 0, stream>>>(xb, wt, bias, cst, qb, kb, mask, out);
  k_logits<<<3456, 256, 0, stream>>>(qb, kb, mask, out);
}